// Round 1
// baseline (628.139 us; speedup 1.0000x reference)
//
#include <hip/hip_runtime.h>
#include <math.h>

#define HD 56
#define WD 56
#define CD 64
#define PLANE 3136   // 56*56

// ---------------- weight transpose: wT[k][c][o] = w[o][c][k] ----------------
__global__ __launch_bounds__(256) void wtrans_k(
    const float* __restrict__ w1, const float* __restrict__ w3, const float* __restrict__ w2,
    float* __restrict__ t1, float* __restrict__ t3, float* __restrict__ t2)
{
    const float* src; float* dst; int K2;
    if (blockIdx.y == 0)      { src = w1; dst = t1; K2 = 9;  }
    else if (blockIdx.y == 1) { src = w3; dst = t3; K2 = 25; }
    else                      { src = w2; dst = t2; K2 = 9;  }
    int total = 64 * 64 * K2;
    for (int idx = blockIdx.x * 256 + threadIdx.x; idx < total; idx += gridDim.x * 256) {
        int k = idx >> 12;           // / 4096
        int c = (idx >> 6) & 63;
        int o = idx & 63;
        dst[idx] = src[(o * 64 + c) * K2 + k];
    }
}

// ---------------- 3x3 offset conv, pad 1, stride 1 ----------------
// grid: (13, Co/COT, B), block 256. Thread = one output pixel, COT output chans.
template<int COT>
__global__ __launch_bounds__(256) void offconv_k(
    const float* __restrict__ src, const float* __restrict__ w,
    const float* __restrict__ bias, float* __restrict__ dst, int Co)
{
    __shared__ float wl[COT * 768];   // [i][c][12] padded (9 -> 12 for aligned vec reads)
    int tid = threadIdx.x;
    int b   = blockIdx.z;
    int co0 = blockIdx.y * COT;

    for (int idx = tid; idx < COT * 768; idx += 256) wl[idx] = 0.f;
    __syncthreads();
    for (int idx = tid; idx < COT * 576; idx += 256) {
        int i   = idx / 576;
        int rem = idx - i * 576;
        int c   = rem / 9;
        int kk  = rem - c * 9;
        wl[i * 768 + c * 12 + kk] = w[(co0 + i) * 576 + rem];
    }
    __syncthreads();

    int pix = blockIdx.x * 256 + tid;
    if (pix >= PLANE) return;
    int ho = pix / WD, wo = pix - ho * WD;

    float acc[COT];
#pragma unroll
    for (int i = 0; i < COT; ++i) acc[i] = bias[co0 + i];

    const float* sb = src + b * (CD * PLANE);
    for (int c = 0; c < CD; ++c) {
        const float* sc = sb + c * PLANE;
        float v[12];
#pragma unroll
        for (int ky = 0; ky < 3; ++ky) {
            int y = ho + ky - 1;
            bool yv = (unsigned)y < (unsigned)HD;
#pragma unroll
            for (int kx = 0; kx < 3; ++kx) {
                int xx = wo + kx - 1;
                v[ky * 3 + kx] = (yv && (unsigned)xx < (unsigned)WD) ? sc[y * WD + xx] : 0.f;
            }
        }
        v[9] = v[10] = v[11] = 0.f;
#pragma unroll
        for (int i = 0; i < COT; ++i) {
            const float* wr = &wl[i * 768 + c * 12];
#pragma unroll
            for (int kk = 0; kk < 12; ++kk) acc[i] += wr[kk] * v[kk];
        }
    }
    float* db = dst + (size_t)(b * Co + co0) * PLANE + pix;
#pragma unroll
    for (int i = 0; i < COT; ++i) db[i * PLANE] = acc[i];
}

// ---------------- deformable conv + BN (+relu/add variants) ----------------
// MODE 0: out = relu(bn(dc))
// MODE 1: out += relu(bn(dc))
// MODE 2: out = relu(bn(dc) + addsrc)
// grid: B*HD blocks (one output row each), 256 threads.
template<int K2, int KW, int PAD, int DIL, int MODE>
__global__ __launch_bounds__(256) void dconv_k(
    const float* __restrict__ x, const float* __restrict__ offs,
    const float* __restrict__ wT,   // [K2][64][64] : wT[k][c][o]
    const float* __restrict__ gamma, const float* __restrict__ beta,
    const float* __restrict__ mean, const float* __restrict__ var,
    const float* __restrict__ addsrc, float* __restrict__ out)
{
    __shared__ float wt[64 * 68];     // w tile for current k: wt[c*68 + o]
    __shared__ float cols[64 * 64];   // cols[c*64 + p] (p padded 56->64)
    __shared__ int   s_o00[WD], s_o01[WD], s_o10[WD], s_o11[WD];
    __shared__ float s_w00[WD], s_w01[WD], s_w10[WD], s_w11[WD];

    int tid = threadIdx.x;
    int row = blockIdx.x;
    int b   = row / HD;
    int ho  = row - b * HD;
    const float* xb = x + b * (CD * PLANE);

    int op = tid & 31;
    int pg = tid >> 5;
    int o0 = op * 2;

    float a0[8], a1[8];
#pragma unroll
    for (int j = 0; j < 8; ++j) { a0[j] = 0.f; a1[j] = 0.f; }

#pragma unroll 1
    for (int k = 0; k < K2; ++k) {
        __syncthreads();   // protect LDS from previous iteration's readers
        if (tid < WD) {
            int wo = tid;
            float dy = offs[((b * (2 * K2) + 2 * k) * HD + ho) * WD + wo];
            float dx = offs[((b * (2 * K2) + 2 * k + 1) * HD + ho) * WD + wo];
            float py = dy + (float)((k / KW) * DIL - PAD + ho);
            float px = dx + (float)((k % KW) * DIL - PAD + wo);
            float fy = floorf(py), fx = floorf(px);
            float wy1 = py - fy, wx1 = px - fx;
            float wy0 = 1.f - wy1, wx0 = 1.f - wx1;
            int y0 = (int)fy, x0 = (int)fx;
            int y1 = y0 + 1, x1 = x0 + 1;
            float vy0 = (y0 >= 0 && y0 < HD) ? 1.f : 0.f;
            float vy1 = (y1 >= 0 && y1 < HD) ? 1.f : 0.f;
            float vx0 = (x0 >= 0 && x0 < WD) ? 1.f : 0.f;
            float vx1 = (x1 >= 0 && x1 < WD) ? 1.f : 0.f;
            int cy0 = min(max(y0, 0), HD - 1), cy1 = min(max(y1, 0), HD - 1);
            int cx0 = min(max(x0, 0), WD - 1), cx1 = min(max(x1, 0), WD - 1);
            s_o00[wo] = cy0 * WD + cx0;
            s_o01[wo] = cy0 * WD + cx1;
            s_o10[wo] = cy1 * WD + cx0;
            s_o11[wo] = cy1 * WD + cx1;
            s_w00[wo] = wy0 * wx0 * vy0 * vx0;
            s_w01[wo] = wy0 * wx1 * vy0 * vx1;
            s_w10[wo] = wy1 * wx0 * vy1 * vx0;
            s_w11[wo] = wy1 * wx1 * vy1 * vx1;
        }
        // stage weight tile for this k (coalesced float4 from pre-transposed wT)
        const float* wk = wT + k * 4096;
#pragma unroll
        for (int i = 0; i < 4; ++i) {
            int base = (tid + i * 256) * 4;
            int c = base >> 6;
            int o = base & 63;
            const float4 wv = *(const float4*)(wk + base);
            *(float4*)&wt[c * 68 + o] = wv;
        }
        __syncthreads();
        // gather bilinear cols tile: cols[c][p]
        for (int idx = tid; idx < CD * WD; idx += 256) {
            int c = idx / WD;
            int p = idx - c * WD;
            const float* sc = xb + c * PLANE;
            float v = s_w00[p] * sc[s_o00[p]] + s_w01[p] * sc[s_o01[p]]
                    + s_w10[p] * sc[s_o10[p]] + s_w11[p] * sc[s_o11[p]];
            cols[c * 64 + p] = v;
        }
        __syncthreads();
        // matmul: acc[o0,o0+1][pg*8 .. +8] += wt[c][o] * cols[c][p]
#pragma unroll 4
        for (int c = 0; c < CD; ++c) {
            float2 wv = *(const float2*)&wt[c * 68 + o0];
            const float* cp = &cols[c * 64 + pg * 8];
            float4 c0 = *(const float4*)cp;
            float4 c1 = *(const float4*)(cp + 4);
            float cv[8] = {c0.x, c0.y, c0.z, c0.w, c1.x, c1.y, c1.z, c1.w};
#pragma unroll
            for (int j = 0; j < 8; ++j) {
                a0[j] += wv.x * cv[j];
                a1[j] += wv.y * cv[j];
            }
        }
    }

    if (pg < 7) {   // pixels pg*8..pg*8+7 all < 56
        int p0 = pg * 8;
        float inv0 = gamma[o0]     * (1.f / sqrtf(var[o0]     + 1e-5f));
        float sh0  = beta[o0]      - mean[o0]     * inv0;
        float inv1 = gamma[o0 + 1] * (1.f / sqrtf(var[o0 + 1] + 1e-5f));
        float sh1  = beta[o0 + 1]  - mean[o0 + 1] * inv1;
        size_t base = ((size_t)(b * 64 + o0) * HD + ho) * WD + p0;
        float* out0 = out + base;
        float* out1 = out0 + PLANE;
#pragma unroll
        for (int j = 0; j < 8; ++j) {
            float v0 = a0[j] * inv0 + sh0;
            float v1 = a1[j] * inv1 + sh1;
            if (MODE == 0) {
                out0[j] = fmaxf(v0, 0.f);
                out1[j] = fmaxf(v1, 0.f);
            } else if (MODE == 1) {
                out0[j] += fmaxf(v0, 0.f);
                out1[j] += fmaxf(v1, 0.f);
            } else {
                const float* as0 = addsrc + base;
                out0[j] = fmaxf(v0 + as0[j], 0.f);
                out1[j] = fmaxf(v1 + as0[j + PLANE], 0.f);
            }
        }
    }
}

extern "C" void kernel_launch(void* const* d_in, const int* in_sizes, int n_in,
                              void* d_out, int out_size, void* d_ws, size_t ws_size,
                              hipStream_t stream) {
    const float* x   = (const float*)d_in[0];
    const float* ow1 = (const float*)d_in[1];
    const float* ob1 = (const float*)d_in[2];
    const float* ow3 = (const float*)d_in[3];
    const float* ob3 = (const float*)d_in[4];
    const float* ow2 = (const float*)d_in[5];
    const float* ob2 = (const float*)d_in[6];
    const float* w1  = (const float*)d_in[7];
    const float* w3  = (const float*)d_in[8];
    const float* w2  = (const float*)d_in[9];
    const float* g1  = (const float*)d_in[10];
    const float* b1  = (const float*)d_in[11];
    const float* m1  = (const float*)d_in[12];
    const float* v1  = (const float*)d_in[13];
    const float* g3  = (const float*)d_in[14];
    const float* b3  = (const float*)d_in[15];
    const float* m3  = (const float*)d_in[16];
    const float* v3  = (const float*)d_in[17];
    const float* g2  = (const float*)d_in[18];
    const float* b2  = (const float*)d_in[19];
    const float* m2  = (const float*)d_in[20];
    const float* v2  = (const float*)d_in[21];

    float* out = (float*)d_out;
    float* ws  = (float*)d_ws;

    float* offs1 = ws;                    // 8*18*3136 = 451584  (reused for offs2)
    float* offs3 = ws + 451584;           // 8*50*3136 = 1254400
    float* mid   = ws + 1705984;          // 8*64*3136 = 1605632
    float* wT1   = ws + 3311616;          // 36864
    float* wT3   = wT1 + 36864;           // 102400
    float* wT2   = wT3 + 102400;          // 36864

    dim3 blk(256);

    wtrans_k<<<dim3(16, 3), blk, 0, stream>>>(w1, w3, w2, wT1, wT3, wT2);

    offconv_k<6><<<dim3(13, 3, 8),  blk, 0, stream>>>(x, ow1, ob1, offs1, 18);
    offconv_k<10><<<dim3(13, 5, 8), blk, 0, stream>>>(x, ow3, ob3, offs3, 50);

    dconv_k<9, 3, 2, 2, 0><<<dim3(8 * HD), blk, 0, stream>>>(
        x, offs1, wT1, g1, b1, m1, v1, nullptr, mid);
    dconv_k<25, 5, 4, 2, 1><<<dim3(8 * HD), blk, 0, stream>>>(
        x, offs3, wT3, g3, b3, m3, v3, nullptr, mid);

    offconv_k<6><<<dim3(13, 3, 8), blk, 0, stream>>>(mid, ow2, ob2, offs1, 18);

    dconv_k<9, 3, 2, 2, 2><<<dim3(8 * HD), blk, 0, stream>>>(
        mid, offs1, wT2, g2, b2, m2, v2, x, out);
}

// Round 3
// 489.409 us; speedup vs baseline: 1.2835x; 1.2835x over previous
//
#include <hip/hip_runtime.h>
#include <math.h>

#define HD 56
#define WD 56
#define CD 64
#define PLANE 3136   // 56*56

// ---------------- weight transpose: wT[k][c][o] = w[o][c][k] ----------------
__global__ __launch_bounds__(256) void wtrans_k(
    const float* __restrict__ w1, const float* __restrict__ w3, const float* __restrict__ w2,
    float* __restrict__ t1, float* __restrict__ t3, float* __restrict__ t2)
{
    const float* src; float* dst; int K2;
    if (blockIdx.y == 0)      { src = w1; dst = t1; K2 = 9;  }
    else if (blockIdx.y == 1) { src = w3; dst = t3; K2 = 25; }
    else                      { src = w2; dst = t2; K2 = 9;  }
    int total = 64 * 64 * K2;
    for (int idx = blockIdx.x * 256 + threadIdx.x; idx < total; idx += gridDim.x * 256) {
        int k = idx >> 12;           // / 4096
        int c = (idx >> 6) & 63;
        int o = idx & 63;
        dst[idx] = src[(o * 64 + c) * K2 + k];
    }
}

// ---------------- 3x3 offset conv, pad 1, stride 1 ----------------
// 1D grid = 13 * NG * 8 blocks; batch = bid & 7 (XCD-local batch working set).
template<int COT>
__global__ __launch_bounds__(256) void offconv_k(
    const float* __restrict__ src, const float* __restrict__ w,
    const float* __restrict__ bias, float* __restrict__ dst, int Co, int NG)
{
    __shared__ float wl[COT * 768];   // [i][c][12] padded
    int tid = threadIdx.x;
    int bid = blockIdx.x;
    int b   = bid & 7;
    int r   = bid >> 3;               // [0, 13*NG)
    int co0 = (r % NG) * COT;
    int pixblk = r / NG;

    for (int idx = tid; idx < COT * 768; idx += 256) wl[idx] = 0.f;
    __syncthreads();
    for (int idx = tid; idx < COT * 576; idx += 256) {
        int i   = idx / 576;
        int rem = idx - i * 576;
        int c   = rem / 9;
        int kk  = rem - c * 9;
        wl[i * 768 + c * 12 + kk] = w[(co0 + i) * 576 + rem];
    }
    __syncthreads();

    int pix = pixblk * 256 + tid;
    if (pix >= PLANE) return;
    int ho = pix / WD, wo = pix - ho * WD;

    float acc[COT];
#pragma unroll
    for (int i = 0; i < COT; ++i) acc[i] = bias[co0 + i];

    const float* sb = src + b * (CD * PLANE);
    for (int c = 0; c < CD; ++c) {
        const float* sc = sb + c * PLANE;
        float v[12];
#pragma unroll
        for (int ky = 0; ky < 3; ++ky) {
            int y = ho + ky - 1;
            bool yv = (unsigned)y < (unsigned)HD;
#pragma unroll
            for (int kx = 0; kx < 3; ++kx) {
                int xx = wo + kx - 1;
                v[ky * 3 + kx] = (yv && (unsigned)xx < (unsigned)WD) ? sc[y * WD + xx] : 0.f;
            }
        }
        v[9] = v[10] = v[11] = 0.f;
#pragma unroll
        for (int i = 0; i < COT; ++i) {
            const float* wr = &wl[i * 768 + c * 12];
#pragma unroll
            for (int kk = 0; kk < 12; ++kk) acc[i] += wr[kk] * v[kk];
        }
    }
    float* db = dst + (size_t)(b * Co + co0) * PLANE + pix;
#pragma unroll
    for (int i = 0; i < COT; ++i) db[i * PLANE] = acc[i];
}

// ---------------- deformable conv + BN ----------------
// MERGED==1: out = relu(bnA(dcA)) + relu(bnB(dcB))   (dc1 3x3 pad2 + dc3 5x5 pad4)
// MERGED==0: out = relu(bnA(dcA) + addsrc)
// grid: 896 blocks = 8 batch x 56 row x 2 half-row; batch = bid & 7 (XCD-local).
// block: 256 threads; thread = 2 out-chans (op) x 4 px (pg), 28 px per block.
template<int MERGED>
__global__ __launch_bounds__(256) void dconv_k(
    const float* __restrict__ x,
    const float* __restrict__ offsA, const float* __restrict__ offsB,
    const float* __restrict__ wTA, const float* __restrict__ wTB,   // [k][c][o]
    const float* __restrict__ gA, const float* __restrict__ bA,
    const float* __restrict__ mA, const float* __restrict__ vA,
    const float* __restrict__ gB, const float* __restrict__ bB,
    const float* __restrict__ mB, const float* __restrict__ vB,
    const float* __restrict__ addsrc, float* __restrict__ out)
{
    __shared__ float wt[64 * 68];     // wt[c*68 + o] for current tap
    __shared__ float cols[64 * 32];   // cols[c*32 + p], p = px - px0, padded to 32
    __shared__ int   s_o00[32], s_o01[32], s_o10[32], s_o11[32];
    __shared__ float s_w00[32], s_w01[32], s_w10[32], s_w11[32];

    int tid = threadIdx.x;
    int bid = blockIdx.x;
    int b   = bid & 7;
    int r   = bid >> 3;
    int ho  = r >> 1;
    int px0 = (r & 1) * 28;

    const float* xb = x + b * (CD * PLANE);
    int op = tid & 31;
    int pg = tid >> 5;
    int o0 = op * 2;

    float aA0[4], aA1[4], aB0[4], aB1[4];
#pragma unroll
    for (int j = 0; j < 4; ++j) { aA0[j] = 0.f; aA1[j] = 0.f; aB0[j] = 0.f; aB1[j] = 0.f; }

    const int NT = MERGED ? 34 : 9;
#pragma unroll 1
    for (int k = 0; k < NT; ++k) {
        bool isA = (!MERGED) || (k < 9);
        int kk   = isA ? k : (k - 9);
        // offsA: (B, 2*9, H, W) -> b stride 18*PLANE ; offsB: (B, 2*25, H, W) -> b stride 50*PLANE
        const float* offs = isA ? (offsA + b * (18 * PLANE)) : (offsB + b * (50 * PLANE));
        const float* wk   = (isA ? wTA : wTB) + kk * 4096;
        int kw  = isA ? 3 : 5;
        int pad = isA ? 2 : 4;

        __syncthreads();   // protect LDS from previous tap's readers
        if (tid < 28) {
            int wo = px0 + tid;
            float dy = offs[(2 * kk)     * PLANE + ho * WD + wo];
            float dx = offs[(2 * kk + 1) * PLANE + ho * WD + wo];
            float py = dy + (float)((kk / kw) * 2 - pad + ho);
            float px = dx + (float)((kk % kw) * 2 - pad + wo);
            float fy = floorf(py), fx = floorf(px);
            float wy1 = py - fy, wx1 = px - fx;
            float wy0 = 1.f - wy1, wx0 = 1.f - wx1;
            int y0 = (int)fy, x0 = (int)fx;
            int y1 = y0 + 1, x1 = x0 + 1;
            float vy0 = (y0 >= 0 && y0 < HD) ? 1.f : 0.f;
            float vy1 = (y1 >= 0 && y1 < HD) ? 1.f : 0.f;
            float vx0 = (x0 >= 0 && x0 < WD) ? 1.f : 0.f;
            float vx1 = (x1 >= 0 && x1 < WD) ? 1.f : 0.f;
            int cy0 = min(max(y0, 0), HD - 1), cy1 = min(max(y1, 0), HD - 1);
            int cx0 = min(max(x0, 0), WD - 1), cx1 = min(max(x1, 0), WD - 1);
            s_o00[tid] = cy0 * WD + cx0;
            s_o01[tid] = cy0 * WD + cx1;
            s_o10[tid] = cy1 * WD + cx0;
            s_o11[tid] = cy1 * WD + cx1;
            s_w00[tid] = wy0 * wx0 * vy0 * vx0;
            s_w01[tid] = wy0 * wx1 * vy0 * vx1;
            s_w10[tid] = wy1 * wx0 * vy1 * vx0;
            s_w11[tid] = wy1 * wx1 * vy1 * vx1;
        }
        // stage weight tile (coalesced float4 from pre-transposed wT, L2-resident)
#pragma unroll
        for (int i = 0; i < 4; ++i) {
            int base = (tid + i * 256) * 4;
            int c = base >> 6;
            int o = base & 63;
            *(float4*)&wt[c * 68 + o] = *(const float4*)(wk + base);
        }
        __syncthreads();
        // gather bilinear cols tile: cols[c][p], p in [0,32), valid p<28
#pragma unroll
        for (int i = 0; i < 8; ++i) {
            int idx = tid + i * 256;
            int c = idx >> 5, p = idx & 31;
            float v = 0.f;
            if (p < 28) {
                const float* sc = xb + c * PLANE;
                v = s_w00[p] * sc[s_o00[p]] + s_w01[p] * sc[s_o01[p]]
                  + s_w10[p] * sc[s_o10[p]] + s_w11[p] * sc[s_o11[p]];
            }
            cols[c * 32 + p] = v;
        }
        __syncthreads();
        // matmul: acc[2 o][4 px] += wt[c][o] * cols[c][p]
        if (isA) {
#pragma unroll 4
            for (int c = 0; c < CD; ++c) {
                float2 wv = *(const float2*)&wt[c * 68 + o0];
                float4 cv = *(const float4*)&cols[c * 32 + pg * 4];
                aA0[0] += wv.x * cv.x; aA0[1] += wv.x * cv.y;
                aA0[2] += wv.x * cv.z; aA0[3] += wv.x * cv.w;
                aA1[0] += wv.y * cv.x; aA1[1] += wv.y * cv.y;
                aA1[2] += wv.y * cv.z; aA1[3] += wv.y * cv.w;
            }
        } else {
#pragma unroll 4
            for (int c = 0; c < CD; ++c) {
                float2 wv = *(const float2*)&wt[c * 68 + o0];
                float4 cv = *(const float4*)&cols[c * 32 + pg * 4];
                aB0[0] += wv.x * cv.x; aB0[1] += wv.x * cv.y;
                aB0[2] += wv.x * cv.z; aB0[3] += wv.x * cv.w;
                aB1[0] += wv.y * cv.x; aB1[1] += wv.y * cv.y;
                aB1[2] += wv.y * cv.z; aB1[3] += wv.y * cv.w;
            }
        }
    }

    if (pg < 7) {   // px0 + pg*4 + 3 <= px0 + 27 < 56
        int px = px0 + pg * 4;
        float invA0 = gA[o0]     * (1.f / sqrtf(vA[o0]     + 1e-5f));
        float shA0  = bA[o0]     - mA[o0]     * invA0;
        float invA1 = gA[o0 + 1] * (1.f / sqrtf(vA[o0 + 1] + 1e-5f));
        float shA1  = bA[o0 + 1] - mA[o0 + 1] * invA1;
        size_t base = ((size_t)(b * 64 + o0) * HD + ho) * WD + px;
        float* out0 = out + base;
        float* out1 = out0 + PLANE;
        if (MERGED) {
            float invB0 = gB[o0]     * (1.f / sqrtf(vB[o0]     + 1e-5f));
            float shB0  = bB[o0]     - mB[o0]     * invB0;
            float invB1 = gB[o0 + 1] * (1.f / sqrtf(vB[o0 + 1] + 1e-5f));
            float shB1  = bB[o0 + 1] - mB[o0 + 1] * invB1;
#pragma unroll
            for (int j = 0; j < 4; ++j) {
                out0[j] = fmaxf(aA0[j] * invA0 + shA0, 0.f) + fmaxf(aB0[j] * invB0 + shB0, 0.f);
                out1[j] = fmaxf(aA1[j] * invA1 + shA1, 0.f) + fmaxf(aB1[j] * invB1 + shB1, 0.f);
            }
        } else {
            const float* as0 = addsrc + base;
#pragma unroll
            for (int j = 0; j < 4; ++j) {
                out0[j] = fmaxf(aA0[j] * invA0 + shA0 + as0[j], 0.f);
                out1[j] = fmaxf(aA1[j] * invA1 + shA1 + as0[j + PLANE], 0.f);
            }
        }
    }
}

extern "C" void kernel_launch(void* const* d_in, const int* in_sizes, int n_in,
                              void* d_out, int out_size, void* d_ws, size_t ws_size,
                              hipStream_t stream) {
    const float* x   = (const float*)d_in[0];
    const float* ow1 = (const float*)d_in[1];
    const float* ob1 = (const float*)d_in[2];
    const float* ow3 = (const float*)d_in[3];
    const float* ob3 = (const float*)d_in[4];
    const float* ow2 = (const float*)d_in[5];
    const float* ob2 = (const float*)d_in[6];
    const float* w1  = (const float*)d_in[7];
    const float* w3  = (const float*)d_in[8];
    const float* w2  = (const float*)d_in[9];
    const float* g1  = (const float*)d_in[10];
    const float* b1  = (const float*)d_in[11];
    const float* m1  = (const float*)d_in[12];
    const float* v1  = (const float*)d_in[13];
    const float* g3  = (const float*)d_in[14];
    const float* b3  = (const float*)d_in[15];
    const float* m3  = (const float*)d_in[16];
    const float* v3  = (const float*)d_in[17];
    const float* g2  = (const float*)d_in[18];
    const float* b2  = (const float*)d_in[19];
    const float* m2  = (const float*)d_in[20];
    const float* v2  = (const float*)d_in[21];

    float* out = (float*)d_out;
    float* ws  = (float*)d_ws;

    float* offs1 = ws;                    // 8*18*3136 = 451584  (reused for offs2)
    float* offs3 = ws + 451584;           // 8*50*3136 = 1254400
    float* mid   = ws + 1705984;          // 8*64*3136 = 1605632
    float* wT1   = ws + 3311616;          // 36864
    float* wT3   = wT1 + 36864;           // 102400
    float* wT2   = wT3 + 102400;          // 36864

    dim3 blk(256);

    wtrans_k<<<dim3(16, 3), blk, 0, stream>>>(w1, w3, w2, wT1, wT3, wT2);

    offconv_k<6><<<dim3(13 * 3 * 8),  blk, 0, stream>>>(x, ow1, ob1, offs1, 18, 3);
    offconv_k<10><<<dim3(13 * 5 * 8), blk, 0, stream>>>(x, ow3, ob3, offs3, 50, 5);

    dconv_k<1><<<dim3(896), blk, 0, stream>>>(
        x, offs1, offs3, wT1, wT3, g1, b1, m1, v1, g3, b3, m3, v3, nullptr, mid);

    offconv_k<6><<<dim3(13 * 3 * 8), blk, 0, stream>>>(mid, ow2, ob2, offs1, 18, 3);

    dconv_k<0><<<dim3(896), blk, 0, stream>>>(
        mid, offs1, nullptr, wT2, nullptr, g2, b2, m2, v2,
        nullptr, nullptr, nullptr, nullptr, x, out);
}

// Round 4
// 442.357 us; speedup vs baseline: 1.4200x; 1.1064x over previous
//
#include <hip/hip_runtime.h>
#include <math.h>

#define HD 56
#define WD 56
#define CD 64
#define PLANE 3136   // 56*56

typedef _Float16 f16x8 __attribute__((ext_vector_type(8)));
typedef float    f32x4 __attribute__((ext_vector_type(4)));

// ---- weight transpose+swizzle+f16: wT[k][o][cs] = (f16)w[o][c][k],
//      cs = ((c>>3) ^ (o&7))*8 + (c&7)   (XOR swizzle at 16B granularity) ----
__global__ __launch_bounds__(256) void wtrans_k(
    const float* __restrict__ w1, const float* __restrict__ w3, const float* __restrict__ w2,
    _Float16* __restrict__ t1, _Float16* __restrict__ t3, _Float16* __restrict__ t2)
{
    const float* src; _Float16* dst; int K2;
    if (blockIdx.y == 0)      { src = w1; dst = t1; K2 = 9;  }
    else if (blockIdx.y == 1) { src = w3; dst = t3; K2 = 25; }
    else                      { src = w2; dst = t2; K2 = 9;  }
    int total = 64 * 64 * K2;
    for (int idx = blockIdx.x * 256 + threadIdx.x; idx < total; idx += gridDim.x * 256) {
        int k  = idx >> 12;
        int o  = (idx >> 6) & 63;
        int cs = idx & 63;
        int cblk = (cs >> 3) ^ (o & 7);
        int c  = cblk * 8 + (cs & 7);
        dst[idx] = (_Float16)src[(o * 64 + c) * K2 + k];
    }
}

// ---------------- 3x3 offset conv (fp32), pad 1, stride 1 ----------------
template<int COT>
__global__ __launch_bounds__(256) void offconv_k(
    const float* __restrict__ src, const float* __restrict__ w,
    const float* __restrict__ bias, float* __restrict__ dst, int Co, int NG)
{
    __shared__ float wl[COT * 768];
    int tid = threadIdx.x;
    int bid = blockIdx.x;
    int b   = bid & 7;
    int r   = bid >> 3;
    int co0 = (r % NG) * COT;
    int pixblk = r / NG;

    for (int idx = tid; idx < COT * 768; idx += 256) wl[idx] = 0.f;
    __syncthreads();
    for (int idx = tid; idx < COT * 576; idx += 256) {
        int i   = idx / 576;
        int rem = idx - i * 576;
        int c   = rem / 9;
        int kk  = rem - c * 9;
        wl[i * 768 + c * 12 + kk] = w[(co0 + i) * 576 + rem];
    }
    __syncthreads();

    int pix = pixblk * 256 + tid;
    if (pix >= PLANE) return;
    int ho = pix / WD, wo = pix - ho * WD;

    float acc[COT];
#pragma unroll
    for (int i = 0; i < COT; ++i) acc[i] = bias[co0 + i];

    const float* sb = src + b * (CD * PLANE);
    for (int c = 0; c < CD; ++c) {
        const float* sc = sb + c * PLANE;
        float v[12];
#pragma unroll
        for (int ky = 0; ky < 3; ++ky) {
            int y = ho + ky - 1;
            bool yv = (unsigned)y < (unsigned)HD;
#pragma unroll
            for (int kx = 0; kx < 3; ++kx) {
                int xx = wo + kx - 1;
                v[ky * 3 + kx] = (yv && (unsigned)xx < (unsigned)WD) ? sc[y * WD + xx] : 0.f;
            }
        }
        v[9] = v[10] = v[11] = 0.f;
#pragma unroll
        for (int i = 0; i < COT; ++i) {
            const float* wr = &wl[i * 768 + c * 12];
#pragma unroll
            for (int kk = 0; kk < 12; ++kk) acc[i] += wr[kk] * v[kk];
        }
    }
    float* db = dst + (size_t)(b * Co + co0) * PLANE + pix;
#pragma unroll
    for (int i = 0; i < COT; ++i) db[i * PLANE] = acc[i];
}

// ---------------- deformable conv + BN, f16 MFMA ----------------
// MERGED==1: out = relu(bnA(dcA)) + relu(bnB(dcB))
// MERGED==0: out = relu(bnA(dcA) + addsrc)
// grid: 896 = 8 batch x 56 row x 2 half-row; batch = bid&7 (XCD-local).
// block: 256 thr = 4 waves; output tile 64 o x 32 px (28 valid).
// wave w: o in [16w,16w+16), p in [0,32) => 2 accum tiles of 16x16.
template<int MERGED>
__global__ __launch_bounds__(256) void dconv_k(
    const float* __restrict__ x,
    const float* __restrict__ offsA, const float* __restrict__ offsB,
    const _Float16* __restrict__ wTA, const _Float16* __restrict__ wTB, // [k][o][cs]
    const float* __restrict__ gA, const float* __restrict__ bA,
    const float* __restrict__ mA, const float* __restrict__ vA,
    const float* __restrict__ gB, const float* __restrict__ bB,
    const float* __restrict__ mB, const float* __restrict__ vB,
    const float* __restrict__ addsrc, float* __restrict__ out)
{
    constexpr int NT = MERGED ? 34 : 9;
    __shared__ __align__(16) _Float16 wt[4096];    // [o][cs] current tap
    __shared__ __align__(16) _Float16 cols[2048];  // [p][cs] current tap
    __shared__ int4   t_idx[NT * 32];              // bilinear gather indices
    __shared__ float4 t_wgt[NT * 32];              // bilinear weights
    __shared__ float  s_inv[MERGED ? 128 : 64];
    __shared__ float  s_sh [MERGED ? 128 : 64];

    int tid = threadIdx.x;
    int bid = blockIdx.x;
    int b   = bid & 7;
    int r   = bid >> 3;
    int ho  = r >> 1;
    int px0 = (r & 1) * 28;

    const float* xb = x + b * (CD * PLANE);

    // BN constants
    if (tid < 64) {
        float iv = gA[tid] * (1.f / sqrtf(vA[tid] + 1e-5f));
        s_inv[tid] = iv;
        s_sh[tid]  = bA[tid] - mA[tid] * iv;
    } else if (MERGED && tid < 128) {
        int o = tid - 64;
        float iv = gB[o] * (1.f / sqrtf(vB[o] + 1e-5f));
        s_inv[tid] = iv;
        s_sh[tid]  = bB[o] - mB[o] * iv;
    }

    // bilinear tables for all taps
    for (int idx = tid; idx < NT * 32; idx += 256) {
        int tap = idx >> 5;
        int p   = idx & 31;
        int kk, kw, pad;
        const float* offs;
        if (!MERGED || tap < 9) { kk = tap;     offs = offsA + b * (18 * PLANE); kw = 3; pad = 2; }
        else                    { kk = tap - 9; offs = offsB + b * (50 * PLANE); kw = 5; pad = 4; }
        int4   oidx = make_int4(0, 0, 0, 0);
        float4 wgt  = make_float4(0.f, 0.f, 0.f, 0.f);
        if (p < 28) {
            int wo = px0 + p;
            float dy = offs[(2 * kk)     * PLANE + ho * WD + wo];
            float dx = offs[(2 * kk + 1) * PLANE + ho * WD + wo];
            float py = dy + (float)((kk / kw) * 2 - pad + ho);
            float px = dx + (float)((kk % kw) * 2 - pad + wo);
            float fy = floorf(py), fx = floorf(px);
            float wy1 = py - fy, wx1 = px - fx;
            float wy0 = 1.f - wy1, wx0 = 1.f - wx1;
            int y0 = (int)fy, x0 = (int)fx;
            int y1 = y0 + 1, x1 = x0 + 1;
            float vy0 = (y0 >= 0 && y0 < HD) ? 1.f : 0.f;
            float vy1 = (y1 >= 0 && y1 < HD) ? 1.f : 0.f;
            float vx0 = (x0 >= 0 && x0 < WD) ? 1.f : 0.f;
            float vx1 = (x1 >= 0 && x1 < WD) ? 1.f : 0.f;
            int cy0 = min(max(y0, 0), HD - 1), cy1 = min(max(y1, 0), HD - 1);
            int cx0 = min(max(x0, 0), WD - 1), cx1 = min(max(x1, 0), WD - 1);
            oidx = make_int4(cy0 * WD + cx0, cy0 * WD + cx1, cy1 * WD + cx0, cy1 * WD + cx1);
            wgt  = make_float4(wy0 * wx0 * vy0 * vx0, wy0 * wx1 * vy0 * vx1,
                               wy1 * wx0 * vy1 * vx0, wy1 * wx1 * vy1 * vx1);
        }
        t_idx[idx] = oidx;
        t_wgt[idx] = wgt;
    }
    __syncthreads();

    int p_lane = tid & 31;        // gather: fixed pixel per thread
    int c0     = tid >> 5;        // gather: channel low bits
    int l      = tid & 63;        // lane in wave
    int w      = tid >> 6;        // wave id
    int g      = l >> 4;          // k-group
    int o_lane = w * 16 + (l & 15);
    int pswz   = p_lane & 7;

    f32x4 accA0 = {0.f, 0.f, 0.f, 0.f}, accA1 = {0.f, 0.f, 0.f, 0.f};
    f32x4 accB0 = {0.f, 0.f, 0.f, 0.f}, accB1 = {0.f, 0.f, 0.f, 0.f};

#pragma unroll 1
    for (int tap = 0; tap < NT; ++tap) {
        bool isA = (!MERGED) || (tap < 9);
        const _Float16* wkg = isA ? (wTA + tap * 4096) : (wTB + (tap - 9) * 4096);

        __syncthreads();   // wt/cols free (previous tap's MFMA done)
        // stage weight tile: linear, pre-swizzled in global
        *(float4*)&wt[tid * 8]        = *(const float4*)&wkg[tid * 8];
        *(float4*)&wt[2048 + tid * 8] = *(const float4*)&wkg[2048 + tid * 8];

        // gather 8 channels for this thread's pixel
        int4   oi = t_idx[tap * 32 + p_lane];
        float4 wg = t_wgt[tap * 32 + p_lane];
#pragma unroll
        for (int i = 0; i < 8; ++i) {
            int c = c0 + i * 8;
            const float* sc = xb + c * PLANE;
            float v = wg.x * sc[oi.x] + wg.y * sc[oi.y]
                    + wg.z * sc[oi.z] + wg.w * sc[oi.w];
            cols[p_lane * 64 + ((i ^ pswz) << 3) + c0] = (_Float16)v;
        }
        __syncthreads();

        // fragments (XOR-swizzled reads, conflict-free)
        int oswz = o_lane & 7;
        f16x8 a0 = *(const f16x8*)&wt[o_lane * 64 + (((0 + g) ^ oswz) << 3)];
        f16x8 a1 = *(const f16x8*)&wt[o_lane * 64 + (((4 + g) ^ oswz) << 3)];
        int pA = (l & 15), pB = 16 + (l & 15);
        f16x8 b00 = *(const f16x8*)&cols[pA * 64 + (((0 + g) ^ (pA & 7)) << 3)];
        f16x8 b01 = *(const f16x8*)&cols[pB * 64 + (((0 + g) ^ (pB & 7)) << 3)];
        f16x8 b10 = *(const f16x8*)&cols[pA * 64 + (((4 + g) ^ (pA & 7)) << 3)];
        f16x8 b11 = *(const f16x8*)&cols[pB * 64 + (((4 + g) ^ (pB & 7)) << 3)];
        if (isA) {
            accA0 = __builtin_amdgcn_mfma_f32_16x16x32_f16(a0, b00, accA0, 0, 0, 0);
            accA1 = __builtin_amdgcn_mfma_f32_16x16x32_f16(a0, b01, accA1, 0, 0, 0);
            accA0 = __builtin_amdgcn_mfma_f32_16x16x32_f16(a1, b10, accA0, 0, 0, 0);
            accA1 = __builtin_amdgcn_mfma_f32_16x16x32_f16(a1, b11, accA1, 0, 0, 0);
        } else {
            accB0 = __builtin_amdgcn_mfma_f32_16x16x32_f16(a0, b00, accB0, 0, 0, 0);
            accB1 = __builtin_amdgcn_mfma_f32_16x16x32_f16(a0, b01, accB1, 0, 0, 0);
            accB0 = __builtin_amdgcn_mfma_f32_16x16x32_f16(a1, b10, accB0, 0, 0, 0);
            accB1 = __builtin_amdgcn_mfma_f32_16x16x32_f16(a1, b11, accB1, 0, 0, 0);
        }
    }

    // epilogue: D tile: row(o) = g*4 + reg, col(p) = l&15
#pragma unroll
    for (int t = 0; t < 2; ++t) {
        int p_local = t * 16 + (l & 15);
        if (p_local >= 28) continue;
        int px = px0 + p_local;
        f32x4 va = t ? accA1 : accA0;
        f32x4 vb = t ? accB1 : accB0;
#pragma unroll
        for (int rr = 0; rr < 4; ++rr) {
            int o_out = w * 16 + g * 4 + rr;
            size_t oidx = ((size_t)(b * 64 + o_out) * HD + ho) * WD + px;
            float vA = va[rr] * s_inv[o_out] + s_sh[o_out];
            if (MERGED) {
                float vB = vb[rr] * s_inv[64 + o_out] + s_sh[64 + o_out];
                out[oidx] = fmaxf(vA, 0.f) + fmaxf(vB, 0.f);
            } else {
                out[oidx] = fmaxf(vA + addsrc[oidx], 0.f);
            }
        }
    }
}

extern "C" void kernel_launch(void* const* d_in, const int* in_sizes, int n_in,
                              void* d_out, int out_size, void* d_ws, size_t ws_size,
                              hipStream_t stream) {
    const float* x   = (const float*)d_in[0];
    const float* ow1 = (const float*)d_in[1];
    const float* ob1 = (const float*)d_in[2];
    const float* ow3 = (const float*)d_in[3];
    const float* ob3 = (const float*)d_in[4];
    const float* ow2 = (const float*)d_in[5];
    const float* ob2 = (const float*)d_in[6];
    const float* w1  = (const float*)d_in[7];
    const float* w3  = (const float*)d_in[8];
    const float* w2  = (const float*)d_in[9];
    const float* g1  = (const float*)d_in[10];
    const float* b1  = (const float*)d_in[11];
    const float* m1  = (const float*)d_in[12];
    const float* v1  = (const float*)d_in[13];
    const float* g3  = (const float*)d_in[14];
    const float* b3  = (const float*)d_in[15];
    const float* m3  = (const float*)d_in[16];
    const float* v3  = (const float*)d_in[17];
    const float* g2  = (const float*)d_in[18];
    const float* b2  = (const float*)d_in[19];
    const float* m2  = (const float*)d_in[20];
    const float* v2  = (const float*)d_in[21];

    float* out = (float*)d_out;
    float* ws  = (float*)d_ws;

    float* offs1 = ws;                    // 8*18*3136 floats (reused for offs2)
    float* offs3 = ws + 451584;           // 8*50*3136
    float* mid   = ws + 1705984;          // 8*64*3136
    float* fbase = ws + 3311616;
    _Float16* wT1h = (_Float16*)fbase;                    // 36864 f16
    _Float16* wT3h = (_Float16*)(fbase + 18432);          // 102400 f16
    _Float16* wT2h = (_Float16*)(fbase + 18432 + 51200);  // 36864 f16

    dim3 blk(256);

    wtrans_k<<<dim3(16, 3), blk, 0, stream>>>(w1, w3, w2, wT1h, wT3h, wT2h);

    offconv_k<6><<<dim3(13 * 3 * 8),  blk, 0, stream>>>(x, ow1, ob1, offs1, 18, 3);
    offconv_k<10><<<dim3(13 * 5 * 8), blk, 0, stream>>>(x, ow3, ob3, offs3, 50, 5);

    dconv_k<1><<<dim3(896), blk, 0, stream>>>(
        x, offs1, offs3, wT1h, wT3h, g1, b1, m1, v1, g3, b3, m3, v3, nullptr, mid);

    offconv_k<6><<<dim3(13 * 3 * 8), blk, 0, stream>>>(mid, ow2, ob2, offs1, 18, 3);

    dconv_k<0><<<dim3(896), blk, 0, stream>>>(
        mid, offs1, nullptr, wT2h, nullptr, g2, b2, m2, v2,
        nullptr, nullptr, nullptr, nullptr, x, out);
}

// Round 5
// 409.583 us; speedup vs baseline: 1.5336x; 1.0800x over previous
//
#include <hip/hip_runtime.h>
#include <math.h>

#define HD 56
#define WD 56
#define CD 64
#define PLANE 3136   // 56*56

typedef _Float16 f16x8 __attribute__((ext_vector_type(8)));
typedef _Float16 f16x4 __attribute__((ext_vector_type(4)));
typedef float    f32x4 __attribute__((ext_vector_type(4)));

// ---- weight transpose+swizzle+f16: wT[k][o][cs] = (f16)w[o][c][k],
//      cs = ((c>>3) ^ (o&7))*8 + (c&7)   (XOR swizzle at 16B granularity) ----
__global__ __launch_bounds__(256) void wtrans_k(
    const float* __restrict__ w1, const float* __restrict__ w3, const float* __restrict__ w2,
    _Float16* __restrict__ t1, _Float16* __restrict__ t3, _Float16* __restrict__ t2)
{
    const float* src; _Float16* dst; int K2;
    if (blockIdx.y == 0)      { src = w1; dst = t1; K2 = 9;  }
    else if (blockIdx.y == 1) { src = w3; dst = t3; K2 = 25; }
    else                      { src = w2; dst = t2; K2 = 9;  }
    int total = 64 * 64 * K2;
    for (int idx = blockIdx.x * 256 + threadIdx.x; idx < total; idx += gridDim.x * 256) {
        int k  = idx >> 12;
        int o  = (idx >> 6) & 63;
        int cs = idx & 63;
        int cblk = (cs >> 3) ^ (o & 7);
        int c  = cblk * 8 + (cs & 7);
        dst[idx] = (_Float16)src[(o * 64 + c) * K2 + k];
    }
}

// ---------------- 3x3 offset conv (fp32), pad 1, stride 1 ----------------
template<int COT>
__global__ __launch_bounds__(256) void offconv_k(
    const float* __restrict__ src, const float* __restrict__ w,
    const float* __restrict__ bias, float* __restrict__ dst, int Co, int NG)
{
    __shared__ float wl[COT * 768];
    int tid = threadIdx.x;
    int bid = blockIdx.x;
    int b   = bid & 7;
    int r   = bid >> 3;
    int co0 = (r % NG) * COT;
    int pixblk = r / NG;

    for (int idx = tid; idx < COT * 768; idx += 256) wl[idx] = 0.f;
    __syncthreads();
    for (int idx = tid; idx < COT * 576; idx += 256) {
        int i   = idx / 576;
        int rem = idx - i * 576;
        int c   = rem / 9;
        int kk  = rem - c * 9;
        wl[i * 768 + c * 12 + kk] = w[(co0 + i) * 576 + rem];
    }
    __syncthreads();

    int pix = pixblk * 256 + tid;
    if (pix >= PLANE) return;
    int ho = pix / WD, wo = pix - ho * WD;

    float acc[COT];
#pragma unroll
    for (int i = 0; i < COT; ++i) acc[i] = bias[co0 + i];

    const float* sb = src + b * (CD * PLANE);
    for (int c = 0; c < CD; ++c) {
        const float* sc = sb + c * PLANE;
        float v[12];
#pragma unroll
        for (int ky = 0; ky < 3; ++ky) {
            int y = ho + ky - 1;
            bool yv = (unsigned)y < (unsigned)HD;
#pragma unroll
            for (int kx = 0; kx < 3; ++kx) {
                int xx = wo + kx - 1;
                v[ky * 3 + kx] = (yv && (unsigned)xx < (unsigned)WD) ? sc[y * WD + xx] : 0.f;
            }
        }
        v[9] = v[10] = v[11] = 0.f;
#pragma unroll
        for (int i = 0; i < COT; ++i) {
            const float* wr = &wl[i * 768 + c * 12];
#pragma unroll
            for (int kk = 0; kk < 12; ++kk) acc[i] += wr[kk] * v[kk];
        }
    }
    float* db = dst + (size_t)(b * Co + co0) * PLANE + pix;
#pragma unroll
    for (int i = 0; i < COT; ++i) db[i * PLANE] = acc[i];
}

// ---------------- deformable conv + BN, f16 MFMA, software-pipelined ----------------
// MERGED==1: out = relu(bnA(dcA)) + relu(bnB(dcB))
// MERGED==0: out = relu(bnA(dcA) + addsrc)
// grid: 896 = 8 batch x 56 row x 2 half-row; batch = bid&7 (XCD-local).
// block: 256 thr = 4 waves; output tile 64 o x 32 px (28 valid).
// Pipeline: while tap t's MFMAs run, tap t+1's weight+gather loads are in flight;
// weighted-sum + LDS writes land after, one barrier per tap.
template<int MERGED>
__global__ __launch_bounds__(256) void dconv_k(
    const float* __restrict__ x,
    const float* __restrict__ offsA, const float* __restrict__ offsB,
    const _Float16* __restrict__ wTA, const _Float16* __restrict__ wTB, // [k][o][cs]
    const float* __restrict__ gA, const float* __restrict__ bA,
    const float* __restrict__ mA, const float* __restrict__ vA,
    const float* __restrict__ gB, const float* __restrict__ bB,
    const float* __restrict__ mB, const float* __restrict__ vB,
    const float* __restrict__ addsrc, float* __restrict__ out)
{
    constexpr int NT = MERGED ? 34 : 9;
    __shared__ __align__(16) _Float16 wtb[2][4096];   // [o][cs] double-buffered
    __shared__ __align__(16) _Float16 colsb[2][2048]; // [p][cs] double-buffered
    __shared__ ushort4 t_i[NT * 32];                  // bilinear idx (u16 x4)
    __shared__ f16x4   t_w[NT * 32];                  // bilinear wgt (f16 x4, 0 if invalid)
    __shared__ float   s_inv[MERGED ? 128 : 64];
    __shared__ float   s_sh [MERGED ? 128 : 64];

    int tid = threadIdx.x;
    int bid = blockIdx.x;
    int b   = bid & 7;
    int r   = bid >> 3;
    int ho  = r >> 1;
    int px0 = (r & 1) * 28;

    const float* xb = x + b * (CD * PLANE);

    // BN constants
    if (tid < 64) {
        float iv = gA[tid] * (1.f / sqrtf(vA[tid] + 1e-5f));
        s_inv[tid] = iv;
        s_sh[tid]  = bA[tid] - mA[tid] * iv;
    } else if (MERGED && tid < 128) {
        int o = tid - 64;
        float iv = gB[o] * (1.f / sqrtf(vB[o] + 1e-5f));
        s_inv[tid] = iv;
        s_sh[tid]  = bB[o] - mB[o] * iv;
    }

    // bilinear tables for all taps (compressed: u16 idx, f16 wgt)
    for (int idx = tid; idx < NT * 32; idx += 256) {
        int tap = idx >> 5;
        int pp  = idx & 31;
        int kk, kw, pad;
        const float* offs;
        if (!MERGED || tap < 9) { kk = tap;     offs = offsA + b * (18 * PLANE); kw = 3; pad = 2; }
        else                    { kk = tap - 9; offs = offsB + b * (50 * PLANE); kw = 5; pad = 4; }
        ushort4 oidx = make_ushort4(0, 0, 0, 0);
        float w00 = 0.f, w01 = 0.f, w10 = 0.f, w11 = 0.f;
        if (pp < 28) {
            int wo = px0 + pp;
            float dy = offs[(2 * kk)     * PLANE + ho * WD + wo];
            float dx = offs[(2 * kk + 1) * PLANE + ho * WD + wo];
            float py = dy + (float)((kk / kw) * 2 - pad + ho);
            float px = dx + (float)((kk % kw) * 2 - pad + wo);
            float fy = floorf(py), fx = floorf(px);
            float wy1 = py - fy, wx1 = px - fx;
            float wy0 = 1.f - wy1, wx0 = 1.f - wx1;
            int y0 = (int)fy, x0 = (int)fx;
            int y1 = y0 + 1, x1 = x0 + 1;
            float vy0 = (y0 >= 0 && y0 < HD) ? 1.f : 0.f;
            float vy1 = (y1 >= 0 && y1 < HD) ? 1.f : 0.f;
            float vx0 = (x0 >= 0 && x0 < WD) ? 1.f : 0.f;
            float vx1 = (x1 >= 0 && x1 < WD) ? 1.f : 0.f;
            int cy0 = min(max(y0, 0), HD - 1), cy1 = min(max(y1, 0), HD - 1);
            int cx0 = min(max(x0, 0), WD - 1), cx1 = min(max(x1, 0), WD - 1);
            oidx = make_ushort4((unsigned short)(cy0 * WD + cx0), (unsigned short)(cy0 * WD + cx1),
                                (unsigned short)(cy1 * WD + cx0), (unsigned short)(cy1 * WD + cx1));
            w00 = wy0 * wx0 * vy0 * vx0; w01 = wy0 * wx1 * vy0 * vx1;
            w10 = wy1 * wx0 * vy1 * vx0; w11 = wy1 * wx1 * vy1 * vx1;
        }
        t_i[idx] = oidx;
        f16x4 tw = {(_Float16)w00, (_Float16)w01, (_Float16)w10, (_Float16)w11};
        t_w[idx] = tw;
    }
    __syncthreads();

    int p      = tid & 31;        // gather pixel
    int c0     = tid >> 5;        // gather channel block (8 consecutive channels)
    int l      = tid & 63;
    int w      = tid >> 6;
    int g      = l >> 4;
    int o_lane = w * 16 + (l & 15);
    int oswz   = o_lane & 7;
    int pA     = l & 15, pB = 16 + (l & 15);
    const float* gbase = xb + c0 * 8 * PLANE;
    int cwoff = p * 64 + ((c0 ^ (p & 7)) << 3);   // swizzled cols write offset

    f32x4 accA0 = {0.f,0.f,0.f,0.f}, accA1 = {0.f,0.f,0.f,0.f};
    f32x4 accB0 = {0.f,0.f,0.f,0.f}, accB1 = {0.f,0.f,0.f,0.f};

    // ---- prologue: stage tap 0 into buffer 0 ----
    {
        const _Float16* wkg = wTA;   // tap 0 is A
        float4 wr0 = *(const float4*)&wkg[tid * 8];
        float4 wr1 = *(const float4*)&wkg[2048 + tid * 8];
        ushort4 oi = t_i[p];
        f16x4   tw = t_w[p];
        float g00[8], g01[8], g10[8], g11[8];
        if (p < 28) {
#pragma unroll
            for (int j = 0; j < 8; ++j) {
                const float* bp = gbase + j * PLANE;
                g00[j] = bp[oi.x]; g01[j] = bp[oi.y]; g10[j] = bp[oi.z]; g11[j] = bp[oi.w];
            }
        } else {
#pragma unroll
            for (int j = 0; j < 8; ++j) { g00[j] = 0.f; g01[j] = 0.f; g10[j] = 0.f; g11[j] = 0.f; }
        }
        float w00 = (float)tw[0], w01 = (float)tw[1], w10 = (float)tw[2], w11 = (float)tw[3];
        f16x8 h;
#pragma unroll
        for (int j = 0; j < 8; ++j)
            h[j] = (_Float16)(w00 * g00[j] + w01 * g01[j] + w10 * g10[j] + w11 * g11[j]);
        *(float4*)&wtb[0][tid * 8]        = wr0;
        *(float4*)&wtb[0][2048 + tid * 8] = wr1;
        *(f16x8*)&colsb[0][cwoff] = h;
    }
    __syncthreads();

    int cur = 0;
#pragma unroll 1
    for (int tap = 0; tap < NT; ++tap) {
        int nxt = cur ^ 1;
        bool haveNext = (tap + 1 < NT);
        float4 wr0, wr1;
        float g00[8], g01[8], g10[8], g11[8];
        f16x4 tw;
        if (haveNext) {
            int t2 = tap + 1;
            const _Float16* wkg = (!MERGED || t2 < 9) ? (wTA + t2 * 4096) : (wTB + (t2 - 9) * 4096);
            wr0 = *(const float4*)&wkg[tid * 8];
            wr1 = *(const float4*)&wkg[2048 + tid * 8];
            ushort4 oi = t_i[t2 * 32 + p];
            tw = t_w[t2 * 32 + p];
            if (p < 28) {
#pragma unroll
                for (int j = 0; j < 8; ++j) {
                    const float* bp = gbase + j * PLANE;
                    g00[j] = bp[oi.x]; g01[j] = bp[oi.y]; g10[j] = bp[oi.z]; g11[j] = bp[oi.w];
                }
            } else {
#pragma unroll
                for (int j = 0; j < 8; ++j) { g00[j] = 0.f; g01[j] = 0.f; g10[j] = 0.f; g11[j] = 0.f; }
            }
        }
        // MFMA on current buffer (XOR-swizzled conflict-free b128 reads)
        const _Float16* wb = wtb[cur];
        const _Float16* cb = colsb[cur];
        f16x8 a0  = *(const f16x8*)&wb[o_lane * 64 + ((g ^ oswz) << 3)];
        f16x8 a1  = *(const f16x8*)&wb[o_lane * 64 + (((4 + g) ^ oswz) << 3)];
        f16x8 b00 = *(const f16x8*)&cb[pA * 64 + ((g ^ (pA & 7)) << 3)];
        f16x8 b01 = *(const f16x8*)&cb[pB * 64 + ((g ^ (pB & 7)) << 3)];
        f16x8 b10 = *(const f16x8*)&cb[pA * 64 + (((4 + g) ^ (pA & 7)) << 3)];
        f16x8 b11 = *(const f16x8*)&cb[pB * 64 + (((4 + g) ^ (pB & 7)) << 3)];
        bool isA = (!MERGED) || (tap < 9);
        if (isA) {
            accA0 = __builtin_amdgcn_mfma_f32_16x16x32_f16(a0, b00, accA0, 0, 0, 0);
            accA1 = __builtin_amdgcn_mfma_f32_16x16x32_f16(a0, b01, accA1, 0, 0, 0);
            accA0 = __builtin_amdgcn_mfma_f32_16x16x32_f16(a1, b10, accA0, 0, 0, 0);
            accA1 = __builtin_amdgcn_mfma_f32_16x16x32_f16(a1, b11, accA1, 0, 0, 0);
        } else {
            accB0 = __builtin_amdgcn_mfma_f32_16x16x32_f16(a0, b00, accB0, 0, 0, 0);
            accB1 = __builtin_amdgcn_mfma_f32_16x16x32_f16(a0, b01, accB1, 0, 0, 0);
            accB0 = __builtin_amdgcn_mfma_f32_16x16x32_f16(a1, b10, accB0, 0, 0, 0);
            accB1 = __builtin_amdgcn_mfma_f32_16x16x32_f16(a1, b11, accB1, 0, 0, 0);
        }
        if (haveNext) {
            float w00 = (float)tw[0], w01 = (float)tw[1], w10 = (float)tw[2], w11 = (float)tw[3];
            f16x8 h;
#pragma unroll
            for (int j = 0; j < 8; ++j)
                h[j] = (_Float16)(w00 * g00[j] + w01 * g01[j] + w10 * g10[j] + w11 * g11[j]);
            *(float4*)&wtb[nxt][tid * 8]        = wr0;
            *(float4*)&wtb[nxt][2048 + tid * 8] = wr1;
            *(f16x8*)&colsb[nxt][cwoff] = h;
        }
        __syncthreads();
        cur = nxt;
    }

    // epilogue: D tile: row(o) = g*4 + reg, col(p) = l&15
#pragma unroll
    for (int t = 0; t < 2; ++t) {
        int p_local = t * 16 + (l & 15);
        if (p_local >= 28) continue;
        int px = px0 + p_local;
        f32x4 va = t ? accA1 : accA0;
        f32x4 vb = t ? accB1 : accB0;
#pragma unroll
        for (int rr = 0; rr < 4; ++rr) {
            int o_out = w * 16 + g * 4 + rr;
            size_t oidx = ((size_t)(b * 64 + o_out) * HD + ho) * WD + px;
            float vA = va[rr] * s_inv[o_out] + s_sh[o_out];
            if (MERGED) {
                float vB = vb[rr] * s_inv[64 + o_out] + s_sh[64 + o_out];
                out[oidx] = fmaxf(vA, 0.f) + fmaxf(vB, 0.f);
            } else {
                out[oidx] = fmaxf(vA + addsrc[oidx], 0.f);
            }
        }
    }
}

extern "C" void kernel_launch(void* const* d_in, const int* in_sizes, int n_in,
                              void* d_out, int out_size, void* d_ws, size_t ws_size,
                              hipStream_t stream) {
    const float* x   = (const float*)d_in[0];
    const float* ow1 = (const float*)d_in[1];
    const float* ob1 = (const float*)d_in[2];
    const float* ow3 = (const float*)d_in[3];
    const float* ob3 = (const float*)d_in[4];
    const float* ow2 = (const float*)d_in[5];
    const float* ob2 = (const float*)d_in[6];
    const float* w1  = (const float*)d_in[7];
    const float* w3  = (const float*)d_in[8];
    const float* w2  = (const float*)d_in[9];
    const float* g1  = (const float*)d_in[10];
    const float* b1  = (const float*)d_in[11];
    const float* m1  = (const float*)d_in[12];
    const float* v1  = (const float*)d_in[13];
    const float* g3  = (const float*)d_in[14];
    const float* b3  = (const float*)d_in[15];
    const float* m3  = (const float*)d_in[16];
    const float* v3  = (const float*)d_in[17];
    const float* g2  = (const float*)d_in[18];
    const float* b2  = (const float*)d_in[19];
    const float* m2  = (const float*)d_in[20];
    const float* v2  = (const float*)d_in[21];

    float* out = (float*)d_out;
    float* ws  = (float*)d_ws;

    float* offs1 = ws;                    // 8*18*3136 floats (reused for offs2)
    float* offs3 = ws + 451584;           // 8*50*3136
    float* mid   = ws + 1705984;          // 8*64*3136
    float* fbase = ws + 3311616;
    _Float16* wT1h = (_Float16*)fbase;                    // 36864 f16
    _Float16* wT3h = (_Float16*)(fbase + 18432);          // 102400 f16
    _Float16* wT2h = (_Float16*)(fbase + 18432 + 51200);  // 36864 f16

    dim3 blk(256);

    wtrans_k<<<dim3(16, 3), blk, 0, stream>>>(w1, w3, w2, wT1h, wT3h, wT2h);

    offconv_k<6><<<dim3(13 * 3 * 8),  blk, 0, stream>>>(x, ow1, ob1, offs1, 18, 3);
    offconv_k<10><<<dim3(13 * 5 * 8), blk, 0, stream>>>(x, ow3, ob3, offs3, 50, 5);

    dconv_k<1><<<dim3(896), blk, 0, stream>>>(
        x, offs1, offs3, wT1h, wT3h, g1, b1, m1, v1, g3, b3, m3, v3, nullptr, mid);

    offconv_k<6><<<dim3(13 * 3 * 8), blk, 0, stream>>>(mid, ow2, ob2, offs1, 18, 3);

    dconv_k<0><<<dim3(896), blk, 0, stream>>>(
        mid, offs1, nullptr, wT2h, nullptr, g2, b2, m2, v2,
        nullptr, nullptr, nullptr, nullptr, x, out);
}

// Round 6
// 408.877 us; speedup vs baseline: 1.5363x; 1.0017x over previous
//
#include <hip/hip_runtime.h>
#include <math.h>

#define HD 56
#define WD 56
#define CD 64
#define PLANE 3136   // 56*56

typedef _Float16 f16x8 __attribute__((ext_vector_type(8)));
typedef _Float16 f16x4 __attribute__((ext_vector_type(4)));
typedef float    f32x4 __attribute__((ext_vector_type(4)));

// ---- weight transpose + f16: wT[k][o][c] = (f16)w[o][c][k] (plain layout) ----
__global__ __launch_bounds__(256) void wtrans_k(
    const float* __restrict__ w1, const float* __restrict__ w3, const float* __restrict__ w2,
    _Float16* __restrict__ t1, _Float16* __restrict__ t3, _Float16* __restrict__ t2)
{
    const float* src; _Float16* dst; int K2;
    if (blockIdx.y == 0)      { src = w1; dst = t1; K2 = 9;  }
    else if (blockIdx.y == 1) { src = w3; dst = t3; K2 = 25; }
    else                      { src = w2; dst = t2; K2 = 9;  }
    int total = 64 * 64 * K2;
    for (int idx = blockIdx.x * 256 + threadIdx.x; idx < total; idx += gridDim.x * 256) {
        int k = idx >> 12;
        int o = (idx >> 6) & 63;
        int c = idx & 63;
        dst[idx] = (_Float16)src[(o * 64 + c) * K2 + k];
    }
}

// ---------------- 3x3 offset conv (fp32), pad 1, stride 1 ----------------
template<int COT>
__global__ __launch_bounds__(256) void offconv_k(
    const float* __restrict__ src, const float* __restrict__ w,
    const float* __restrict__ bias, float* __restrict__ dst, int Co, int NG)
{
    __shared__ float wl[COT * 768];
    int tid = threadIdx.x;
    int bid = blockIdx.x;
    int b   = bid & 7;
    int r   = bid >> 3;
    int co0 = (r % NG) * COT;
    int pixblk = r / NG;

    for (int idx = tid; idx < COT * 768; idx += 256) wl[idx] = 0.f;
    __syncthreads();
    for (int idx = tid; idx < COT * 576; idx += 256) {
        int i   = idx / 576;
        int rem = idx - i * 576;
        int c   = rem / 9;
        int kk  = rem - c * 9;
        wl[i * 768 + c * 12 + kk] = w[(co0 + i) * 576 + rem];
    }
    __syncthreads();

    int pix = pixblk * 256 + tid;
    if (pix >= PLANE) return;
    int ho = pix / WD, wo = pix - ho * WD;

    float acc[COT];
#pragma unroll
    for (int i = 0; i < COT; ++i) acc[i] = bias[co0 + i];

    const float* sb = src + b * (CD * PLANE);
    for (int c = 0; c < CD; ++c) {
        const float* sc = sb + c * PLANE;
        float v[12];
#pragma unroll
        for (int ky = 0; ky < 3; ++ky) {
            int y = ho + ky - 1;
            bool yv = (unsigned)y < (unsigned)HD;
#pragma unroll
            for (int kx = 0; kx < 3; ++kx) {
                int xx = wo + kx - 1;
                v[ky * 3 + kx] = (yv && (unsigned)xx < (unsigned)WD) ? sc[y * WD + xx] : 0.f;
            }
        }
        v[9] = v[10] = v[11] = 0.f;
#pragma unroll
        for (int i = 0; i < COT; ++i) {
            const float* wr = &wl[i * 768 + c * 12];
#pragma unroll
            for (int kk = 0; kk < 12; ++kk) acc[i] += wr[kk] * v[kk];
        }
    }
    float* db = dst + (size_t)(b * Co + co0) * PLANE + pix;
#pragma unroll
    for (int i = 0; i < COT; ++i) db[i * PLANE] = acc[i];
}

// ---------------- deformable conv + BN, f16 MFMA, high-occupancy ----------------
// MERGED==1: out = relu(bnA(dcA)) + relu(bnB(dcB))
// MERGED==0: out = relu(bnA(dcA) + addsrc)
// grid: 1792 = 8 batch x 56 row x 4 quarter-row; batch = bid&7 (XCD-local).
// block: 128 thr = 2 waves; tile 64 o x 14 px (16 padded).
// Wave w: o in [32w, 32w+32) (two 16-o A-tiles), all 16 px.
// Weights: per-lane A-fragments loaded straight global->reg (no LDS).
// Cols: XOR-swizzled LDS, double-buffered; 1 barrier per tap.
template<int MERGED>
__global__ __launch_bounds__(128) void dconv_k(
    const float* __restrict__ x,
    const float* __restrict__ offsA, const float* __restrict__ offsB,
    const _Float16* __restrict__ wTA, const _Float16* __restrict__ wTB, // [k][o][c]
    const float* __restrict__ gA, const float* __restrict__ bA,
    const float* __restrict__ mA, const float* __restrict__ vA,
    const float* __restrict__ gB, const float* __restrict__ bB,
    const float* __restrict__ mB, const float* __restrict__ vB,
    const float* __restrict__ addsrc, float* __restrict__ out)
{
    constexpr int NT = MERGED ? 34 : 9;
    __shared__ __align__(16) _Float16 colsb[2][1024];  // [p<16][c 64] swizzled
    __shared__ ushort4 t_i[NT * 16];                   // bilinear idx
    __shared__ f16x4   t_w[NT * 16];                   // bilinear wgt (0 if invalid)
    __shared__ float   s_inv[MERGED ? 128 : 64];
    __shared__ float   s_sh [MERGED ? 128 : 64];

    int tid = threadIdx.x;
    int bid = blockIdx.x;
    int b   = bid & 7;
    int r   = bid >> 3;
    int ho  = r >> 2;
    int px0 = (r & 3) * 14;

    const float* xb = x + b * (CD * PLANE);

    // BN constants
    if (tid < 64) {
        float iv = gA[tid] * (1.f / sqrtf(vA[tid] + 1e-5f));
        s_inv[tid] = iv;
        s_sh[tid]  = bA[tid] - mA[tid] * iv;
    } else if (MERGED) {
        int o = tid - 64;
        float iv = gB[o] * (1.f / sqrtf(vB[o] + 1e-5f));
        s_inv[tid] = iv;
        s_sh[tid]  = bB[o] - mB[o] * iv;
    }

    // bilinear tables for all taps
    for (int idx = tid; idx < NT * 16; idx += 128) {
        int tap = idx >> 4;
        int pp  = idx & 15;
        int kk, kw, pad;
        const float* offs;
        if (!MERGED || tap < 9) { kk = tap;     offs = offsA + b * (18 * PLANE); kw = 3; pad = 2; }
        else                    { kk = tap - 9; offs = offsB + b * (50 * PLANE); kw = 5; pad = 4; }
        ushort4 oidx = make_ushort4(0, 0, 0, 0);
        float w00 = 0.f, w01 = 0.f, w10 = 0.f, w11 = 0.f;
        if (pp < 14) {
            int wo = px0 + pp;
            float dy = offs[(2 * kk)     * PLANE + ho * WD + wo];
            float dx = offs[(2 * kk + 1) * PLANE + ho * WD + wo];
            float py = dy + (float)((kk / kw) * 2 - pad + ho);
            float px = dx + (float)((kk % kw) * 2 - pad + wo);
            float fy = floorf(py), fx = floorf(px);
            float wy1 = py - fy, wx1 = px - fx;
            float wy0 = 1.f - wy1, wx0 = 1.f - wx1;
            int y0 = (int)fy, x0 = (int)fx;
            int y1 = y0 + 1, x1 = x0 + 1;
            float vy0 = (y0 >= 0 && y0 < HD) ? 1.f : 0.f;
            float vy1 = (y1 >= 0 && y1 < HD) ? 1.f : 0.f;
            float vx0 = (x0 >= 0 && x0 < WD) ? 1.f : 0.f;
            float vx1 = (x1 >= 0 && x1 < WD) ? 1.f : 0.f;
            int cy0 = min(max(y0, 0), HD - 1), cy1 = min(max(y1, 0), HD - 1);
            int cx0 = min(max(x0, 0), WD - 1), cx1 = min(max(x1, 0), WD - 1);
            oidx = make_ushort4((unsigned short)(cy0 * WD + cx0), (unsigned short)(cy0 * WD + cx1),
                                (unsigned short)(cy1 * WD + cx0), (unsigned short)(cy1 * WD + cx1));
            w00 = wy0 * wx0 * vy0 * vx0; w01 = wy0 * wx1 * vy0 * vx1;
            w10 = wy1 * wx0 * vy1 * vx0; w11 = wy1 * wx1 * vy1 * vx1;
        }
        t_i[idx] = oidx;
        f16x4 tw = {(_Float16)w00, (_Float16)w01, (_Float16)w10, (_Float16)w11};
        t_w[idx] = tw;
    }
    __syncthreads();

    int p  = tid & 15;            // gather pixel
    int c0 = tid >> 4;            // gather channel block (8 consecutive channels)
    int l  = tid & 63;
    int w  = tid >> 6;            // wave id (0..1)
    int g  = l >> 4;              // k-group (0..3)
    int pA = l & 15;
    const float* gbase = xb + c0 * 8 * PLANE;
    int cwoff = p * 64 + ((c0 ^ (p & 7)) << 3);      // swizzled cols write offset
    int woff0 = (w * 32 + (l & 15)) * 64 + g * 8;    // A-frag: o-tile0
    int woff1 = woff0 + 16 * 64;                     // A-frag: o-tile1
    int boff0 = pA * 64 + ((g ^ (pA & 7)) << 3);     // B-frag k-half0
    int boff1 = pA * 64 + (((4 + g) ^ (pA & 7)) << 3); // B-frag k-half1

    f32x4 accA0 = {0.f,0.f,0.f,0.f}, accA1 = {0.f,0.f,0.f,0.f};
    f32x4 accB0 = {0.f,0.f,0.f,0.f}, accB1 = {0.f,0.f,0.f,0.f};

    f16x8 a00, a01, a10, a11;   // current tap A-fragments (o-tile, k-half)

    // ---- prologue: tap 0 (always A) ----
    {
        const _Float16* wk = wTA;
        a00 = *(const f16x8*)&wk[woff0];
        a01 = *(const f16x8*)&wk[woff0 + 32];
        a10 = *(const f16x8*)&wk[woff1];
        a11 = *(const f16x8*)&wk[woff1 + 32];
        ushort4 oi = t_i[p];
        f16x4   tw = t_w[p];
        float g00[8], g01[8], g10[8], g11[8];
        if (p < 14) {
#pragma unroll
            for (int j = 0; j < 8; ++j) {
                const float* bp = gbase + j * PLANE;
                g00[j] = bp[oi.x]; g01[j] = bp[oi.y]; g10[j] = bp[oi.z]; g11[j] = bp[oi.w];
            }
        } else {
#pragma unroll
            for (int j = 0; j < 8; ++j) { g00[j]=0.f; g01[j]=0.f; g10[j]=0.f; g11[j]=0.f; }
        }
        float w00 = (float)tw[0], w01 = (float)tw[1], w10 = (float)tw[2], w11 = (float)tw[3];
        f16x8 h;
#pragma unroll
        for (int j = 0; j < 8; ++j)
            h[j] = (_Float16)(w00 * g00[j] + w01 * g01[j] + w10 * g10[j] + w11 * g11[j]);
        *(f16x8*)&colsb[0][cwoff] = h;
    }
    __syncthreads();

    int cur = 0;
#pragma unroll 1
    for (int tap = 0; tap < NT; ++tap) {
        int nxt = cur ^ 1;
        bool haveNext = (tap + 1 < NT);
        f16x8 a00n, a01n, a10n, a11n;
        float g00[8], g01[8], g10[8], g11[8];
        f16x4 tw;
        if (haveNext) {
            int t2 = tap + 1;
            const _Float16* wk = (!MERGED || t2 < 9) ? (wTA + t2 * 4096) : (wTB + (t2 - 9) * 4096);
            a00n = *(const f16x8*)&wk[woff0];
            a01n = *(const f16x8*)&wk[woff0 + 32];
            a10n = *(const f16x8*)&wk[woff1];
            a11n = *(const f16x8*)&wk[woff1 + 32];
            ushort4 oi = t_i[t2 * 16 + p];
            tw = t_w[t2 * 16 + p];
            if (p < 14) {
#pragma unroll
                for (int j = 0; j < 8; ++j) {
                    const float* bp = gbase + j * PLANE;
                    g00[j] = bp[oi.x]; g01[j] = bp[oi.y]; g10[j] = bp[oi.z]; g11[j] = bp[oi.w];
                }
            } else {
#pragma unroll
                for (int j = 0; j < 8; ++j) { g00[j]=0.f; g01[j]=0.f; g10[j]=0.f; g11[j]=0.f; }
            }
        }
        // MFMA on current cols buffer
        const _Float16* cb = colsb[cur];
        f16x8 b0 = *(const f16x8*)&cb[boff0];
        f16x8 b1 = *(const f16x8*)&cb[boff1];
        bool isA = (!MERGED) || (tap < 9);
        if (isA) {
            accA0 = __builtin_amdgcn_mfma_f32_16x16x32_f16(a00, b0, accA0, 0, 0, 0);
            accA1 = __builtin_amdgcn_mfma_f32_16x16x32_f16(a10, b0, accA1, 0, 0, 0);
            accA0 = __builtin_amdgcn_mfma_f32_16x16x32_f16(a01, b1, accA0, 0, 0, 0);
            accA1 = __builtin_amdgcn_mfma_f32_16x16x32_f16(a11, b1, accA1, 0, 0, 0);
        } else {
            accB0 = __builtin_amdgcn_mfma_f32_16x16x32_f16(a00, b0, accB0, 0, 0, 0);
            accB1 = __builtin_amdgcn_mfma_f32_16x16x32_f16(a10, b0, accB1, 0, 0, 0);
            accB0 = __builtin_amdgcn_mfma_f32_16x16x32_f16(a01, b1, accB0, 0, 0, 0);
            accB1 = __builtin_amdgcn_mfma_f32_16x16x32_f16(a11, b1, accB1, 0, 0, 0);
        }
        if (haveNext) {
            float w00 = (float)tw[0], w01 = (float)tw[1], w10 = (float)tw[2], w11 = (float)tw[3];
            f16x8 h;
#pragma unroll
            for (int j = 0; j < 8; ++j)
                h[j] = (_Float16)(w00 * g00[j] + w01 * g01[j] + w10 * g10[j] + w11 * g11[j]);
            *(f16x8*)&colsb[nxt][cwoff] = h;
            a00 = a00n; a01 = a01n; a10 = a10n; a11 = a11n;
        }
        __syncthreads();
        cur = nxt;
    }

    // epilogue: D tile: col(px) = l&15, row(o) = g*4 + rr (per 16-o tile)
    int p_local = l & 15;
    if (p_local < 14) {
        int px = px0 + p_local;
#pragma unroll
        for (int t = 0; t < 2; ++t) {
            f32x4 va = t ? accA1 : accA0;
            f32x4 vb = t ? accB1 : accB0;
#pragma unroll
            for (int rr = 0; rr < 4; ++rr) {
                int o_out = w * 32 + t * 16 + g * 4 + rr;
                size_t oidx = ((size_t)(b * 64 + o_out) * HD + ho) * WD + px;
                float vA = va[rr] * s_inv[o_out] + s_sh[o_out];
                if (MERGED) {
                    float vB = vb[rr] * s_inv[64 + o_out] + s_sh[64 + o_out];
                    out[oidx] = fmaxf(vA, 0.f) + fmaxf(vB, 0.f);
                } else {
                    out[oidx] = fmaxf(vA + addsrc[oidx], 0.f);
                }
            }
        }
    }
}

extern "C" void kernel_launch(void* const* d_in, const int* in_sizes, int n_in,
                              void* d_out, int out_size, void* d_ws, size_t ws_size,
                              hipStream_t stream) {
    const float* x   = (const float*)d_in[0];
    const float* ow1 = (const float*)d_in[1];
    const float* ob1 = (const float*)d_in[2];
    const float* ow3 = (const float*)d_in[3];
    const float* ob3 = (const float*)d_in[4];
    const float* ow2 = (const float*)d_in[5];
    const float* ob2 = (const float*)d_in[6];
    const float* w1  = (const float*)d_in[7];
    const float* w3  = (const float*)d_in[8];
    const float* w2  = (const float*)d_in[9];
    const float* g1  = (const float*)d_in[10];
    const float* b1  = (const float*)d_in[11];
    const float* m1  = (const float*)d_in[12];
    const float* v1  = (const float*)d_in[13];
    const float* g3  = (const float*)d_in[14];
    const float* b3  = (const float*)d_in[15];
    const float* m3  = (const float*)d_in[16];
    const float* v3  = (const float*)d_in[17];
    const float* g2  = (const float*)d_in[18];
    const float* b2  = (const float*)d_in[19];
    const float* m2  = (const float*)d_in[20];
    const float* v2  = (const float*)d_in[21];

    float* out = (float*)d_out;
    float* ws  = (float*)d_ws;

    float* offs1 = ws;                    // 8*18*3136 floats (reused for offs2)
    float* offs3 = ws + 451584;           // 8*50*3136
    float* mid   = ws + 1705984;          // 8*64*3136
    float* fbase = ws + 3311616;
    _Float16* wT1h = (_Float16*)fbase;                    // 36864 f16
    _Float16* wT3h = (_Float16*)(fbase + 18432);          // 102400 f16
    _Float16* wT2h = (_Float16*)(fbase + 18432 + 51200);  // 36864 f16

    wtrans_k<<<dim3(16, 3), dim3(256), 0, stream>>>(w1, w3, w2, wT1h, wT3h, wT2h);

    offconv_k<6><<<dim3(13 * 3 * 8),  dim3(256), 0, stream>>>(x, ow1, ob1, offs1, 18, 3);
    offconv_k<10><<<dim3(13 * 5 * 8), dim3(256), 0, stream>>>(x, ow3, ob3, offs3, 50, 5);

    dconv_k<1><<<dim3(1792), dim3(128), 0, stream>>>(
        x, offs1, offs3, wT1h, wT3h, g1, b1, m1, v1, g3, b3, m3, v3, nullptr, mid);

    offconv_k<6><<<dim3(13 * 3 * 8), dim3(256), 0, stream>>>(mid, ow2, ob2, offs1, 18, 3);

    dconv_k<0><<<dim3(1792), dim3(128), 0, stream>>>(
        mid, offs1, nullptr, wT2h, nullptr, g2, b2, m2, v2,
        nullptr, nullptr, nullptr, nullptr, x, out);
}